// Round 1
// baseline (2976.754 us; speedup 1.0000x reference)
//
#include <hip/hip_runtime.h>

#define NA 50000
#define NP 50000
#define NE 800000
#define D 128
#define OUTD 32

// ---------------- degree / misc ----------------

__global__ __launch_bounds__(256) void degree_count_kernel(
    const int* __restrict__ dst, float* __restrict__ cnt, int nE)
{
    int i = blockIdx.x * 256 + threadIdx.x;
    if (i < nE) atomicAdd(&cnt[dst[i]], 1.0f);
}

__global__ __launch_bounds__(256) void invd_kernel(float* __restrict__ c, int n)
{
    int i = blockIdx.x * 256 + threadIdx.x;
    if (i < n) c[i] = 1.0f / fmaxf(c[i], 1.0f);
}

__global__ __launch_bounds__(256) void add_mat_kernel(
    const float* __restrict__ a, const float* __restrict__ b,
    float* __restrict__ o, int n)
{
    int i = blockIdx.x * 256 + threadIdx.x;
    if (i < n) o[i] = a[i] + b[i];
}

// ---------------- scatter-mean (scaled scatter-add) ----------------
// one wave per edge; lane handles 2 consecutive feature dims

__global__ __launch_bounds__(256) void scatter_kernel(
    const float* __restrict__ xsrc, const int* __restrict__ src,
    const int* __restrict__ dst, const float* __restrict__ invd,
    float* __restrict__ agg, int nE)
{
    int gid = blockIdx.x * 256 + threadIdx.x;
    int e = gid >> 6;
    if (e >= nE) return;
    int lane = gid & 63;
    int s = src[e];
    int d = dst[e];
    float sc = invd[d];
    float2 v = *(const float2*)&xsrc[s * D + lane * 2];
    float* base = agg + d * D + lane * 2;
    atomicAdd(base + 0, v.x * sc);
    atomicAdd(base + 1, v.y * sc);
}

// ---------------- fused multi-segment f32 GEMM ----------------
// C[M x 128] = sum_s A_s[M x 128] @ W_s[128 x 128]  (+bias0 +bias1, leaky relu)
// BM=64 BN=128 BK=32, 256 threads, each thread 4x8 outputs

__global__ __launch_bounds__(256) void gemm_fused(
    const float* __restrict__ A0, const float* __restrict__ W0,
    const float* __restrict__ A1, const float* __restrict__ W1,
    const float* __restrict__ A2, const float* __restrict__ W2,
    int nseg,
    const float* __restrict__ bias0, const float* __restrict__ bias1,
    float* __restrict__ C, int M, int applyRelu)
{
    __shared__ float As[32][68];   // [k][m], pad 68 keeps rows 16B-aligned
    __shared__ float Ws[32][128];  // [k][n]

    const int t = threadIdx.x;
    const int tc = t & 15;         // col group: cols tc*8 .. +7
    const int tr = t >> 4;         // row group: rows tr*4 .. +3
    const int brow = blockIdx.x * 64;

    float acc[4][8];
#pragma unroll
    for (int i = 0; i < 4; ++i)
#pragma unroll
        for (int j = 0; j < 8; ++j) acc[i][j] = 0.f;

    for (int s = 0; s < nseg; ++s) {
        const float* A = (s == 0) ? A0 : ((s == 1) ? A1 : A2);
        const float* W = (s == 0) ? W0 : ((s == 1) ? W1 : W2);
        for (int kk = 0; kk < 128; kk += 32) {
            __syncthreads();
            // stage A chunk: 64 rows x 32 k, transposed into As[k][m]
#pragma unroll
            for (int i = 0; i < 2; ++i) {
                int q = t + i * 256;          // 512 float4 total
                int r = q >> 3;
                int c4 = q & 7;
                int grow = brow + r;
                float4 v = make_float4(0.f, 0.f, 0.f, 0.f);
                if (grow < M) v = *(const float4*)&A[grow * 128 + kk + c4 * 4];
                As[c4 * 4 + 0][r] = v.x;
                As[c4 * 4 + 1][r] = v.y;
                As[c4 * 4 + 2][r] = v.z;
                As[c4 * 4 + 3][r] = v.w;
            }
            // stage W chunk: 32 k x 128 n
#pragma unroll
            for (int i = 0; i < 4; ++i) {
                int q = t + i * 256;          // 1024 float4 total
                int kr = q >> 5;
                int c4 = q & 31;
                *(float4*)&Ws[kr][c4 * 4] = *(const float4*)&W[(kk + kr) * 128 + c4 * 4];
            }
            __syncthreads();
#pragma unroll
            for (int k = 0; k < 32; ++k) {
                float4 av = *(const float4*)&As[k][tr * 4];
                float4 b0 = *(const float4*)&Ws[k][tc * 8];
                float4 b1 = *(const float4*)&Ws[k][tc * 8 + 4];
                float a_[4] = {av.x, av.y, av.z, av.w};
                float b_[8] = {b0.x, b0.y, b0.z, b0.w, b1.x, b1.y, b1.z, b1.w};
#pragma unroll
                for (int im = 0; im < 4; ++im)
#pragma unroll
                    for (int jn = 0; jn < 8; ++jn)
                        acc[im][jn] += a_[im] * b_[jn];
            }
        }
    }

    // epilogue: bias + leaky relu + store
#pragma unroll
    for (int im = 0; im < 4; ++im) {
        int grow = brow + tr * 4 + im;
        if (grow >= M) continue;
#pragma unroll
        for (int j = 0; j < 8; j += 4) {
            int col = tc * 8 + j;
            float4 v;
            v.x = acc[im][j + 0] + bias0[col + 0];
            v.y = acc[im][j + 1] + bias0[col + 1];
            v.z = acc[im][j + 2] + bias0[col + 2];
            v.w = acc[im][j + 3] + bias0[col + 3];
            if (bias1) {
                v.x += bias1[col + 0];
                v.y += bias1[col + 1];
                v.z += bias1[col + 2];
                v.w += bias1[col + 3];
            }
            if (applyRelu) {
                v.x = v.x > 0.f ? v.x : 0.01f * v.x;
                v.y = v.y > 0.f ? v.y : 0.01f * v.y;
                v.z = v.z > 0.f ? v.z : 0.01f * v.z;
                v.w = v.w > 0.f ? v.w : 0.01f * v.w;
            }
            *(float4*)&C[grow * 128 + col] = v;
        }
    }
}

// ---------------- final projection: out = A @ linW + linb ----------------

__global__ __launch_bounds__(256) void final_kernel(
    const float* __restrict__ A, const float* __restrict__ W,
    const float* __restrict__ b, float* __restrict__ out, int M)
{
    __shared__ float As[8][128];
    int t = threadIdx.x;
    int row0 = blockIdx.x * 8;
    {
        int r = t >> 5;
        int c4 = t & 31;
        int grow = row0 + r;
        float4 v = make_float4(0.f, 0.f, 0.f, 0.f);
        if (grow < M) v = *(const float4*)&A[grow * D + c4 * 4];
        *(float4*)&As[r][c4 * 4] = v;
    }
    __syncthreads();
    int r = t >> 5;
    int c = t & 31;
    float acc = 0.f;
#pragma unroll
    for (int k = 0; k < D; ++k)
        acc += As[r][k] * W[k * OUTD + c];
    if (row0 + r < M)
        out[(row0 + r) * OUTD + c] = acc + b[c];
}

// ---------------- launch ----------------

extern "C" void kernel_launch(void* const* d_in, const int* in_sizes, int n_in,
                              void* d_out, int out_size, void* d_ws, size_t ws_size,
                              hipStream_t stream)
{
    const float* x_author = (const float*)d_in[0];
    const float* x_paper  = (const float*)d_in[1];
    const int*   e_w      = (const int*)d_in[2];   // author -> paper
    const int*   e_wb     = (const int*)d_in[3];   // paper  -> author
    const int*   e_c      = (const int*)d_in[4];   // paper  -> paper
    const float* Wl       = (const float*)d_in[5]; // [2,3,128,128]
    const float* bl       = (const float*)d_in[6]; // [2,3,128]
    const float* Wr       = (const float*)d_in[7]; // [2,3,128,128]
    const float* linW     = (const float*)d_in[8]; // [128,32]
    const float* linb     = (const float*)d_in[9]; // [32]
    float* out = (float*)d_out;

    float* w      = (float*)d_ws;
    float* cnt_w  = w;                       // 50000 (papers, writes dst)
    float* cnt_c  = w + 50000;               // 50000 (papers, cites dst)
    float* cnt_wb = w + 100000;              // 50000 (authors, written_by dst)
    float* Wsum   = w + 150000;              // 16384
    float* agg_w  = w + 150000 + 16384;      // NP*D (later reused as a2)
    float* agg_c  = agg_w + (size_t)NP * D;  // NP*D
    float* agg_wb = agg_c + (size_t)NP * D;  // NA*D
    float* a1     = agg_wb + (size_t)NA * D; // NA*D
    float* p1     = a1 + (size_t)NA * D;     // NP*D

    // zero counters + aggregation buffers (every call: harness doesn't re-poison)
    hipMemsetAsync(cnt_w, 0, 3 * 50000 * sizeof(float), stream);
    hipMemsetAsync(agg_w, 0, (size_t)3 * 50000 * D * sizeof(float), stream);

    // degrees -> 1/max(cnt,1)
    int eb = (NE + 255) / 256;
    degree_count_kernel<<<eb, 256, 0, stream>>>(e_w + NE, cnt_w, NE);
    degree_count_kernel<<<eb, 256, 0, stream>>>(e_c + NE, cnt_c, NE);
    degree_count_kernel<<<eb, 256, 0, stream>>>(e_wb + NE, cnt_wb, NE);
    invd_kernel<<<(3 * 50000 + 255) / 256, 256, 0, stream>>>(cnt_w, 3 * 50000);

    // layer-0 aggregations (scaled by 1/deg during scatter)
    int sb = (int)(((long long)NE * 64 + 255) / 256);
    scatter_kernel<<<sb, 256, 0, stream>>>(x_author, e_w, e_w + NE, cnt_w, agg_w, NE);
    scatter_kernel<<<sb, 256, 0, stream>>>(x_paper, e_c, e_c + NE, cnt_c, agg_c, NE);
    scatter_kernel<<<sb, 256, 0, stream>>>(x_paper, e_wb, e_wb + NE, cnt_wb, agg_wb, NE);

    // Wsum = Wr[0,0] + Wr[0,2] (both multiply x_paper in the paper update)
    add_mat_kernel<<<(D * D + 255) / 256, 256, 0, stream>>>(
        Wr + 0 * D * D, Wr + 2 * D * D, Wsum, D * D);

    int gb = (50000 + 63) / 64;
    // p1 = lrelu(agg_w@Wl[0,0] + agg_c@Wl[0,2] + x_paper@Wsum + bl[0,0]+bl[0,2])
    gemm_fused<<<gb, 256, 0, stream>>>(agg_w, Wl, agg_c, Wl + 2 * D * D, x_paper, Wsum, 3,
                                       bl, bl + 2 * D, p1, NP, 1);
    // a1 = lrelu(agg_wb@Wl[0,1] + x_author@Wr[0,1] + bl[0,1])
    gemm_fused<<<gb, 256, 0, stream>>>(agg_wb, Wl + 1 * D * D, x_author, Wr + 1 * D * D,
                                       nullptr, nullptr, 2,
                                       bl + 1 * D, nullptr, a1, NA, 1);

    // ---- layer 1: only authors matter for the output ----
    hipMemsetAsync(agg_wb, 0, (size_t)NA * D * sizeof(float), stream);
    scatter_kernel<<<sb, 256, 0, stream>>>(p1, e_wb, e_wb + NE, cnt_wb, agg_wb, NE);

    float* a2 = agg_w;  // safe reuse: layer-0 paper GEMM already consumed agg_w
    // a2 = lrelu(agg_wb@Wl[1,1] + a1@Wr[1,1] + bl[1,1])
    gemm_fused<<<gb, 256, 0, stream>>>(agg_wb, Wl + 4 * D * D, a1, Wr + 4 * D * D,
                                       nullptr, nullptr, 2,
                                       bl + 4 * D, nullptr, a2, NA, 1);

    // out = a2 @ linW + linb
    final_kernel<<<(NA + 7) / 8, 256, 0, stream>>>(a2, linW, linb, out, NA);
}

// Round 2
// 706.538 us; speedup vs baseline: 4.2132x; 4.2132x over previous
//
#include <hip/hip_runtime.h>

#define NA 50000
#define NP 50000
#define NE 800000
#define D 128
#define OUTD 32
#define NSEG 150000   // 3 relations x 50000 dst nodes

// ---------------- CSR build ----------------

__global__ __launch_bounds__(256) void count_kernel(
    const int* __restrict__ dst, int* __restrict__ cnt, int nE)
{
    int i = blockIdx.x * 256 + threadIdx.x;
    if (i < nE) atomicAdd(&cnt[dst[i]], 1);
}

// per-1024-chunk exclusive scan, block totals out
__global__ __launch_bounds__(1024) void scanA(
    const int* __restrict__ cnt, int* __restrict__ S, int* __restrict__ bsum, int n)
{
    __shared__ int wsum[16];
    int t = threadIdx.x;
    int gi = blockIdx.x * 1024 + t;
    int v = (gi < n) ? cnt[gi] : 0;
    int lane = t & 63, wid = t >> 6;
    int x = v;
#pragma unroll
    for (int off = 1; off < 64; off <<= 1) {
        int y = __shfl_up(x, off, 64);
        if (lane >= off) x += y;
    }
    if (lane == 63) wsum[wid] = x;
    __syncthreads();
    if (wid == 0) {
        int w = (lane < 16) ? wsum[lane] : 0;
#pragma unroll
        for (int off = 1; off < 16; off <<= 1) {
            int y = __shfl_up(w, off, 64);
            if (lane >= off) w += y;
        }
        if (lane < 16) wsum[lane] = w;
    }
    __syncthreads();
    int woff = (wid > 0) ? wsum[wid - 1] : 0;
    int incl = x + woff;
    if (gi < n) S[gi] = incl - v;            // exclusive within block
    if (t == 1023) bsum[blockIdx.x] = incl;  // block total
}

__global__ __launch_bounds__(256) void scanB(int* __restrict__ bsum, int nb)
{
    __shared__ int sh[256];
    int t = threadIdx.x;
    int v = (t < nb) ? bsum[t] : 0;
    sh[t] = v;
    __syncthreads();
    for (int off = 1; off < 256; off <<= 1) {
        int y = (t >= off) ? sh[t - off] : 0;
        __syncthreads();
        sh[t] += y;
        __syncthreads();
    }
    if (t < nb) bsum[t] = sh[t] - v;  // exclusive
}

__global__ __launch_bounds__(1024) void scanC(
    int* __restrict__ S, const int* __restrict__ bsum, int n, int total)
{
    int gi = blockIdx.x * 1024 + threadIdx.x;
    if (gi < n) S[gi] += bsum[blockIdx.x];
    if (gi == 0) S[n] = total;
}

__global__ __launch_bounds__(256) void fill_kernel(
    const int* __restrict__ src, const int* __restrict__ dst,
    const int* __restrict__ rowptr, int* __restrict__ cursor,
    int* __restrict__ csr, int nE)
{
    int i = blockIdx.x * 256 + threadIdx.x;
    if (i >= nE) return;
    int d = dst[i];
    int pos = atomicAdd(&cursor[d], 1);
    csr[rowptr[d] + pos] = src[i];
}

// ---------------- gather-mean: one wave per dst node ----------------

__global__ __launch_bounds__(256) void gather_kernel(
    const float* __restrict__ x, const int* __restrict__ rowptr,
    const int* __restrict__ csr, float* __restrict__ out, int n)
{
    int wid = (blockIdx.x * 256 + threadIdx.x) >> 6;
    if (wid >= n) return;
    int lane = threadIdx.x & 63;
    int beg = rowptr[wid], end = rowptr[wid + 1];
    float ax = 0.f, ay = 0.f, bx = 0.f, by = 0.f;
    int j = beg;
    for (; j + 2 <= end; j += 2) {
        int s0 = csr[j], s1 = csr[j + 1];
        float2 v0 = *(const float2*)&x[(size_t)s0 * D + lane * 2];
        float2 v1 = *(const float2*)&x[(size_t)s1 * D + lane * 2];
        ax += v0.x; ay += v0.y; bx += v1.x; by += v1.y;
    }
    if (j < end) {
        int s0 = csr[j];
        float2 v0 = *(const float2*)&x[(size_t)s0 * D + lane * 2];
        ax += v0.x; ay += v0.y;
    }
    float sc = (end > beg) ? 1.0f / (float)(end - beg) : 0.f;
    float2 r;
    r.x = (ax + bx) * sc;
    r.y = (ay + by) * sc;
    *(float2*)&out[(size_t)wid * D + lane * 2] = r;
}

// ---------------- misc ----------------

__global__ __launch_bounds__(256) void add_mat_kernel(
    const float* __restrict__ a, const float* __restrict__ b,
    float* __restrict__ o, int n)
{
    int i = blockIdx.x * 256 + threadIdx.x;
    if (i < n) o[i] = a[i] + b[i];
}

// ---------------- fused multi-segment f32 GEMM ----------------
// C[M x 128] = sum_s A_s[M x 128] @ W_s[128 x 128]  (+bias0 +bias1, leaky relu)

__global__ __launch_bounds__(256) void gemm_fused(
    const float* __restrict__ A0, const float* __restrict__ W0,
    const float* __restrict__ A1, const float* __restrict__ W1,
    const float* __restrict__ A2, const float* __restrict__ W2,
    int nseg,
    const float* __restrict__ bias0, const float* __restrict__ bias1,
    float* __restrict__ C, int M, int applyRelu)
{
    __shared__ float As[32][68];
    __shared__ float Ws[32][128];

    const int t = threadIdx.x;
    const int tc = t & 15;
    const int tr = t >> 4;
    const int brow = blockIdx.x * 64;

    float acc[4][8];
#pragma unroll
    for (int i = 0; i < 4; ++i)
#pragma unroll
        for (int j = 0; j < 8; ++j) acc[i][j] = 0.f;

    for (int s = 0; s < nseg; ++s) {
        const float* A = (s == 0) ? A0 : ((s == 1) ? A1 : A2);
        const float* W = (s == 0) ? W0 : ((s == 1) ? W1 : W2);
        for (int kk = 0; kk < 128; kk += 32) {
            __syncthreads();
#pragma unroll
            for (int i = 0; i < 2; ++i) {
                int q = t + i * 256;
                int r = q >> 3;
                int c4 = q & 7;
                int grow = brow + r;
                float4 v = make_float4(0.f, 0.f, 0.f, 0.f);
                if (grow < M) v = *(const float4*)&A[grow * 128 + kk + c4 * 4];
                As[c4 * 4 + 0][r] = v.x;
                As[c4 * 4 + 1][r] = v.y;
                As[c4 * 4 + 2][r] = v.z;
                As[c4 * 4 + 3][r] = v.w;
            }
#pragma unroll
            for (int i = 0; i < 4; ++i) {
                int q = t + i * 256;
                int kr = q >> 5;
                int c4 = q & 31;
                *(float4*)&Ws[kr][c4 * 4] = *(const float4*)&W[(kk + kr) * 128 + c4 * 4];
            }
            __syncthreads();
#pragma unroll
            for (int k = 0; k < 32; ++k) {
                float4 av = *(const float4*)&As[k][tr * 4];
                float4 b0 = *(const float4*)&Ws[k][tc * 8];
                float4 b1 = *(const float4*)&Ws[k][tc * 8 + 4];
                float a_[4] = {av.x, av.y, av.z, av.w};
                float b_[8] = {b0.x, b0.y, b0.z, b0.w, b1.x, b1.y, b1.z, b1.w};
#pragma unroll
                for (int im = 0; im < 4; ++im)
#pragma unroll
                    for (int jn = 0; jn < 8; ++jn)
                        acc[im][jn] += a_[im] * b_[jn];
            }
        }
    }

#pragma unroll
    for (int im = 0; im < 4; ++im) {
        int grow = brow + tr * 4 + im;
        if (grow >= M) continue;
#pragma unroll
        for (int j = 0; j < 8; j += 4) {
            int col = tc * 8 + j;
            float4 v;
            v.x = acc[im][j + 0] + bias0[col + 0];
            v.y = acc[im][j + 1] + bias0[col + 1];
            v.z = acc[im][j + 2] + bias0[col + 2];
            v.w = acc[im][j + 3] + bias0[col + 3];
            if (bias1) {
                v.x += bias1[col + 0];
                v.y += bias1[col + 1];
                v.z += bias1[col + 2];
                v.w += bias1[col + 3];
            }
            if (applyRelu) {
                v.x = v.x > 0.f ? v.x : 0.01f * v.x;
                v.y = v.y > 0.f ? v.y : 0.01f * v.y;
                v.z = v.z > 0.f ? v.z : 0.01f * v.z;
                v.w = v.w > 0.f ? v.w : 0.01f * v.w;
            }
            *(float4*)&C[grow * 128 + col] = v;
        }
    }
}

// ---------------- final projection ----------------

__global__ __launch_bounds__(256) void final_kernel(
    const float* __restrict__ A, const float* __restrict__ W,
    const float* __restrict__ b, float* __restrict__ out, int M)
{
    __shared__ float As[8][128];
    int t = threadIdx.x;
    int row0 = blockIdx.x * 8;
    {
        int r = t >> 5;
        int c4 = t & 31;
        int grow = row0 + r;
        float4 v = make_float4(0.f, 0.f, 0.f, 0.f);
        if (grow < M) v = *(const float4*)&A[grow * D + c4 * 4];
        *(float4*)&As[r][c4 * 4] = v;
    }
    __syncthreads();
    int r = t >> 5;
    int c = t & 31;
    float acc = 0.f;
#pragma unroll
    for (int k = 0; k < D; ++k)
        acc += As[r][k] * W[k * OUTD + c];
    if (row0 + r < M)
        out[(row0 + r) * OUTD + c] = acc + b[c];
}

// ---------------- launch ----------------

extern "C" void kernel_launch(void* const* d_in, const int* in_sizes, int n_in,
                              void* d_out, int out_size, void* d_ws, size_t ws_size,
                              hipStream_t stream)
{
    const float* x_author = (const float*)d_in[0];
    const float* x_paper  = (const float*)d_in[1];
    const int*   e_w      = (const int*)d_in[2];   // author -> paper   (rel 0)
    const int*   e_wb     = (const int*)d_in[3];   // paper  -> author  (rel 2)
    const int*   e_c      = (const int*)d_in[4];   // paper  -> paper   (rel 1)
    const float* Wl       = (const float*)d_in[5]; // [2,3,128,128]
    const float* bl       = (const float*)d_in[6]; // [2,3,128]
    const float* Wr       = (const float*)d_in[7]; // [2,3,128,128]
    const float* linW     = (const float*)d_in[8]; // [128,32]
    const float* linb     = (const float*)d_in[9]; // [32]
    float* out = (float*)d_out;

    // ---- workspace layout ----
    int* ib      = (int*)d_ws;
    int* cnt     = ib;                 // 150000
    int* cursor  = ib + 150000;        // 150000
    int* S       = ib + 300000;        // 150001
    int* bsum    = ib + 450001;        // 256 (rounded region)
    int* csr     = ib + 450304;        // 2400000
    float* fb    = (float*)(ib + 2850304);   // 16B-aligned
    float* Wsum  = fb;                 // 16384
    float* buf0  = fb + 16384;         // 6.4M floats each
    float* buf1  = buf0 + (size_t)NP * D;
    float* buf2  = buf1 + (size_t)NP * D;
    float* buf3  = buf2 + (size_t)NP * D;

    // zero counters + cursors
    hipMemsetAsync(ib, 0, 300000 * sizeof(int), stream);

    // ---- degree histograms (segment order: 0=writes, 1=cites, 2=written_by) ----
    int eb = (NE + 255) / 256;
    count_kernel<<<eb, 256, 0, stream>>>(e_w + NE, cnt + 0 * 50000, NE);
    count_kernel<<<eb, 256, 0, stream>>>(e_c + NE, cnt + 1 * 50000, NE);
    count_kernel<<<eb, 256, 0, stream>>>(e_wb + NE, cnt + 2 * 50000, NE);

    // ---- exclusive scan over 150000 counts ----
    int nb = (NSEG + 1023) / 1024;  // 147
    scanA<<<nb, 1024, 0, stream>>>(cnt, S, bsum, NSEG);
    scanB<<<1, 256, 0, stream>>>(bsum, nb);
    scanC<<<nb, 1024, 0, stream>>>(S, bsum, NSEG, 3 * NE);

    // ---- fill CSR ----
    fill_kernel<<<eb, 256, 0, stream>>>(e_w, e_w + NE, S + 0 * 50000, cursor + 0 * 50000, csr, NE);
    fill_kernel<<<eb, 256, 0, stream>>>(e_c, e_c + NE, S + 1 * 50000, cursor + 1 * 50000, csr, NE);
    fill_kernel<<<eb, 256, 0, stream>>>(e_wb, e_wb + NE, S + 2 * 50000, cursor + 2 * 50000, csr, NE);

    // ---- layer-0 gathers ----
    int gbl = (50000 * 64 + 255) / 256;  // one wave per dst node
    gather_kernel<<<gbl, 256, 0, stream>>>(x_author, S + 0 * 50000, csr, buf0, NP); // agg writes
    gather_kernel<<<gbl, 256, 0, stream>>>(x_paper,  S + 1 * 50000, csr, buf1, NP); // agg cites
    gather_kernel<<<gbl, 256, 0, stream>>>(x_paper,  S + 2 * 50000, csr, buf2, NA); // agg written_by

    // Wsum = Wr[0,0] + Wr[0,2]
    add_mat_kernel<<<(D * D + 255) / 256, 256, 0, stream>>>(
        Wr + 0 * D * D, Wr + 2 * D * D, Wsum, D * D);

    int gb = (50000 + 63) / 64;
    // p1 (buf3) = lrelu(agg_w@Wl[0,0] + agg_c@Wl[0,2] + x_paper@Wsum + bl[0,0]+bl[0,2])
    gemm_fused<<<gb, 256, 0, stream>>>(buf0, Wl + 0 * D * D, buf1, Wl + 2 * D * D,
                                       x_paper, Wsum, 3,
                                       bl + 0 * D, bl + 2 * D, buf3, NP, 1);
    // a1 (buf0) = lrelu(agg_wb@Wl[0,1] + x_author@Wr[0,1] + bl[0,1])
    gemm_fused<<<gb, 256, 0, stream>>>(buf2, Wl + 1 * D * D, x_author, Wr + 1 * D * D,
                                       nullptr, nullptr, 2,
                                       bl + 1 * D, nullptr, buf0, NA, 1);

    // ---- layer 1 (papers never consumed downstream) ----
    gather_kernel<<<gbl, 256, 0, stream>>>(buf3, S + 2 * 50000, csr, buf1, NA); // agg written_by of p1

    // a2 (buf2) = lrelu(g2@Wl[1,1] + a1@Wr[1,1] + bl[1,1])
    gemm_fused<<<gb, 256, 0, stream>>>(buf1, Wl + 4 * D * D, buf0, Wr + 4 * D * D,
                                       nullptr, nullptr, 2,
                                       bl + 4 * D, nullptr, buf2, NA, 1);

    // out = a2 @ linW + linb
    final_kernel<<<(NA + 7) / 8, 256, 0, stream>>>(buf2, linW, linb, out, NA);
}

// Round 3
// 475.189 us; speedup vs baseline: 6.2644x; 1.4869x over previous
//
#include <hip/hip_runtime.h>

#define NA 50000
#define NP 50000
#define NE 800000
#define D 128
#define OUTD 32
#define NSEG 150000
#define DD (D * D)

typedef float f32x4 __attribute__((ext_vector_type(4)));
typedef short s16x8 __attribute__((ext_vector_type(8)));

__device__ __forceinline__ ushort f2b(float f) {
    uint x = __float_as_uint(f);
    x += ((x >> 16) & 1u) + 0x7fffu;   // round-to-nearest-even
    return (ushort)(x >> 16);
}
__device__ __forceinline__ float b2f(ushort u) {
    return __uint_as_float(((uint)u) << 16);
}

// ---------------- CSR build ----------------

__global__ __launch_bounds__(256) void count_kernel(
    const int* __restrict__ dst, int* __restrict__ cnt, int nE)
{
    int i = blockIdx.x * 256 + threadIdx.x;
    if (i < nE) atomicAdd(&cnt[dst[i]], 1);
}

__global__ __launch_bounds__(1024) void scanA(
    const int* __restrict__ cnt, int* __restrict__ S, int* __restrict__ bsum, int n)
{
    __shared__ int wsum[16];
    int t = threadIdx.x;
    int gi = blockIdx.x * 1024 + t;
    int v = (gi < n) ? cnt[gi] : 0;
    int lane = t & 63, wid = t >> 6;
    int x = v;
#pragma unroll
    for (int off = 1; off < 64; off <<= 1) {
        int y = __shfl_up(x, off, 64);
        if (lane >= off) x += y;
    }
    if (lane == 63) wsum[wid] = x;
    __syncthreads();
    if (wid == 0) {
        int w = (lane < 16) ? wsum[lane] : 0;
#pragma unroll
        for (int off = 1; off < 16; off <<= 1) {
            int y = __shfl_up(w, off, 64);
            if (lane >= off) w += y;
        }
        if (lane < 16) wsum[lane] = w;
    }
    __syncthreads();
    int woff = (wid > 0) ? wsum[wid - 1] : 0;
    int incl = x + woff;
    if (gi < n) S[gi] = incl - v;
    if (t == 1023) bsum[blockIdx.x] = incl;
}

__global__ __launch_bounds__(256) void scanB(int* __restrict__ bsum, int nb)
{
    __shared__ int sh[256];
    int t = threadIdx.x;
    int v = (t < nb) ? bsum[t] : 0;
    sh[t] = v;
    __syncthreads();
    for (int off = 1; off < 256; off <<= 1) {
        int y = (t >= off) ? sh[t - off] : 0;
        __syncthreads();
        sh[t] += y;
        __syncthreads();
    }
    if (t < nb) bsum[t] = sh[t] - v;
}

__global__ __launch_bounds__(1024) void scanC(
    int* __restrict__ S, const int* __restrict__ bsum, int n, int total)
{
    int gi = blockIdx.x * 1024 + threadIdx.x;
    if (gi < n) S[gi] += bsum[blockIdx.x];
    if (gi == 0) S[n] = total;
}

__global__ __launch_bounds__(256) void fill_kernel(
    const int* __restrict__ src, const int* __restrict__ dst,
    const int* __restrict__ rowptr, int* __restrict__ cursor,
    int* __restrict__ csr, int nE)
{
    int i = blockIdx.x * 256 + threadIdx.x;
    if (i >= nE) return;
    int d = dst[i];
    int pos = atomicAdd(&cursor[d], 1);
    csr[rowptr[d] + pos] = src[i];
}

// ---------------- prep: x -> bf16 ----------------

__global__ __launch_bounds__(256) void cvt_x_kernel(
    const float* __restrict__ xa, const float* __restrict__ xp,
    ushort* __restrict__ oa, ushort* __restrict__ op)
{
    int i = blockIdx.x * 256 + threadIdx.x;   // float4 index
    const int per = NA * D / 4;               // 1.6M
    const float* src; ushort* dst; int li;
    if (i < per) { src = xa; dst = oa; li = i; }
    else { src = xp; dst = op; li = i - per; }
    float4 v = *(const float4*)&src[(size_t)li * 4];
    ushort4 o;
    o.x = f2b(v.x); o.y = f2b(v.y); o.z = f2b(v.z); o.w = f2b(v.w);
    *(ushort4*)&dst[(size_t)li * 4] = o;
}

// ---------------- prep: weights -> bf16 transposed ----------------
// wt[j][n*128+k] = W_j[k][n];  job7 = linW^T (32x128); job8 = bias sum

__global__ __launch_bounds__(256) void prep_w_kernel(
    const float* __restrict__ Wl, const float* __restrict__ Wr,
    const float* __restrict__ linW, const float* __restrict__ bl,
    ushort* __restrict__ wt, float* __restrict__ bsum_p)
{
    int b = blockIdx.x, t = threadIdx.x;
    if (b < 448) {
        int job = b >> 6;
        int idx = (b & 63) * 256 + t;
        int n = idx >> 7, k = idx & 127;
        const float* src;
        float add = 0.f;
        switch (job) {
            case 0: src = Wl + 0 * DD; break;                       // Wl[0,0]
            case 1: src = Wl + 2 * DD; break;                       // Wl[0,2]
            case 2: src = Wr + 0 * DD; add = Wr[2 * DD + k * D + n]; break; // Wr00+Wr02
            case 3: src = Wl + 1 * DD; break;                       // Wl[0,1]
            case 4: src = Wr + 1 * DD; break;                       // Wr[0,1]
            case 5: src = Wl + 4 * DD; break;                       // Wl[1,1]
            default: src = Wr + 4 * DD; break;                      // Wr[1,1]
        }
        wt[(size_t)job * DD + idx] = f2b(src[k * D + n] + add);
    } else if (b < 464) {
        int idx = (b - 448) * 256 + t;    // 4096: n<32, k<128
        int n = idx >> 7, k = idx & 127;
        wt[(size_t)7 * DD + idx] = f2b(linW[k * OUTD + n]);
    } else {
        if (t < D) bsum_p[t] = bl[t] + bl[2 * D + t];
    }
}

// ---------------- gather-mean (bf16 in/out, f32 accum) ----------------

__global__ __launch_bounds__(256) void gather_bf16(
    const ushort* __restrict__ x, const int* __restrict__ rowptr,
    const int* __restrict__ csr, ushort* __restrict__ out, int n)
{
    int wid = (blockIdx.x * 256 + threadIdx.x) >> 6;
    if (wid >= n) return;
    int lane = threadIdx.x & 63;
    int beg = __builtin_amdgcn_readfirstlane(rowptr[wid]);
    int end = __builtin_amdgcn_readfirstlane(rowptr[wid + 1]);
    float ax = 0.f, ay = 0.f, bx = 0.f, by = 0.f;
    int j = beg;
    for (; j + 4 <= end; j += 4) {
        int s0 = csr[j], s1 = csr[j + 1], s2 = csr[j + 2], s3 = csr[j + 3];
        uint u0 = *(const uint*)&x[(size_t)s0 * D + lane * 2];
        uint u1 = *(const uint*)&x[(size_t)s1 * D + lane * 2];
        uint u2 = *(const uint*)&x[(size_t)s2 * D + lane * 2];
        uint u3 = *(const uint*)&x[(size_t)s3 * D + lane * 2];
        ax += __uint_as_float(u0 << 16); ay += __uint_as_float(u0 & 0xffff0000u);
        bx += __uint_as_float(u1 << 16); by += __uint_as_float(u1 & 0xffff0000u);
        ax += __uint_as_float(u2 << 16); ay += __uint_as_float(u2 & 0xffff0000u);
        bx += __uint_as_float(u3 << 16); by += __uint_as_float(u3 & 0xffff0000u);
    }
    for (; j < end; ++j) {
        int s0 = csr[j];
        uint u0 = *(const uint*)&x[(size_t)s0 * D + lane * 2];
        ax += __uint_as_float(u0 << 16); ay += __uint_as_float(u0 & 0xffff0000u);
    }
    float sc = (end > beg) ? 1.0f / (float)(end - beg) : 0.f;
    float rx = (ax + bx) * sc, ry = (ay + by) * sc;
    uint pk = (uint)f2b(rx) | ((uint)f2b(ry) << 16);
    *(uint*)&out[(size_t)wid * D + lane * 2] = pk;
}

// ---------------- MFMA bf16 multi-segment GEMM ----------------
// C[M x 128] = lrelu( sum_s A_s @ W_s + bias )   (A bf16 row-major, W as W^T bf16)
// BM=64, BN=128, 4 waves: wave (wr=w>>1, wc=w&1) -> rows wr*32+.., cols wc*64+..
// If fout != null: additionally out = C @ linW + linb (C kept in LDS, not stored)

#define LDA 136   // row stride in ushort (272 B = 17 x 16 B)

__global__ __launch_bounds__(256) void gemm_mfma(
    const ushort* __restrict__ A0, const ushort* __restrict__ WT0,
    const ushort* __restrict__ A1, const ushort* __restrict__ WT1,
    const ushort* __restrict__ A2, const ushort* __restrict__ WT2,
    int nseg, const float* __restrict__ bias,
    ushort* __restrict__ C,
    const ushort* __restrict__ linWT, const float* __restrict__ linb,
    float* __restrict__ fout, int M)
{
    __shared__ ushort As[64 * LDA];

    const int t = threadIdx.x;
    const int w = t >> 6;
    const int l = t & 63;
    const int wr = w >> 1, wc = w & 1;
    const int l15 = l & 15, l4 = l >> 4;
    const int brow = blockIdx.x * 64;

    f32x4 acc[2][4];
#pragma unroll
    for (int i = 0; i < 2; ++i)
#pragma unroll
        for (int j = 0; j < 4; ++j) acc[i][j] = (f32x4){0.f, 0.f, 0.f, 0.f};

    for (int s = 0; s < nseg; ++s) {
        const ushort* A = (s == 0) ? A0 : ((s == 1) ? A1 : A2);
        const ushort* WT = (s == 0) ? WT0 : ((s == 1) ? WT1 : WT2);

        if (s) __syncthreads();
        // stage A tile: 64 rows x 128 k (bf16), rows padded to LDA
#pragma unroll
        for (int it = 0; it < 4; ++it) {
            int f = it * 256 + t;           // 16B chunk id
            int row = f >> 4, cc = f & 15;
            int grow = brow + row;
            float4 v = make_float4(0.f, 0.f, 0.f, 0.f);
            if (grow < M) v = *(const float4*)&A[(size_t)grow * D + cc * 8];
            *(float4*)&As[row * LDA + cc * 8] = v;
        }
        // preload W^T fragments for this wave's 64 cols (L1-hot)
        s16x8 Bf[4][4];
#pragma unroll
        for (int ni = 0; ni < 4; ++ni)
#pragma unroll
            for (int ks = 0; ks < 4; ++ks)
                Bf[ni][ks] = *(const s16x8*)&WT[(size_t)(wc * 64 + ni * 16 + l15) * D + ks * 32 + l4 * 8];
        __syncthreads();

#pragma unroll
        for (int ks = 0; ks < 4; ++ks) {
            s16x8 af[2];
#pragma unroll
            for (int mi = 0; mi < 2; ++mi)
                af[mi] = *(const s16x8*)&As[(wr * 32 + mi * 16 + l15) * LDA + ks * 32 + l4 * 8];
#pragma unroll
            for (int mi = 0; mi < 2; ++mi)
#pragma unroll
                for (int ni = 0; ni < 4; ++ni)
                    acc[mi][ni] = __builtin_amdgcn_mfma_f32_16x16x32_bf16(
                        af[mi], Bf[ni][ks], acc[mi][ni], 0, 0, 0);
        }
    }

    // epilogue: bias + leaky-relu
    if (!fout) {
#pragma unroll
        for (int mi = 0; mi < 2; ++mi) {
#pragma unroll
            for (int ni = 0; ni < 4; ++ni) {
                int col = wc * 64 + ni * 16 + l15;
                float bb = bias[col];
#pragma unroll
                for (int r = 0; r < 4; ++r) {
                    int grow = brow + wr * 32 + mi * 16 + l4 * 4 + r;
                    if (grow >= M) continue;
                    float v = acc[mi][ni][r] + bb;
                    v = v > 0.f ? v : 0.01f * v;
                    C[(size_t)grow * D + col] = f2b(v);
                }
            }
        }
    } else {
        // keep lrelu'd result in LDS, then fuse final projection (N=32, K=128)
        __syncthreads();
#pragma unroll
        for (int mi = 0; mi < 2; ++mi) {
#pragma unroll
            for (int ni = 0; ni < 4; ++ni) {
                int col = wc * 64 + ni * 16 + l15;
                float bb = bias[col];
#pragma unroll
                for (int r = 0; r < 4; ++r) {
                    int row = wr * 32 + mi * 16 + l4 * 4 + r;
                    float v = acc[mi][ni][r] + bb;
                    v = v > 0.f ? v : 0.01f * v;
                    As[row * LDA + col] = f2b(v);
                }
            }
        }
        __syncthreads();
        // wave w handles rows w*16..+15, all 32 out cols
        f32x4 a2c[2];
        a2c[0] = (f32x4){0.f, 0.f, 0.f, 0.f};
        a2c[1] = (f32x4){0.f, 0.f, 0.f, 0.f};
#pragma unroll
        for (int ks = 0; ks < 4; ++ks) {
            s16x8 af = *(const s16x8*)&As[(w * 16 + l15) * LDA + ks * 32 + l4 * 8];
#pragma unroll
            for (int ni = 0; ni < 2; ++ni) {
                s16x8 bf = *(const s16x8*)&linWT[(size_t)(ni * 16 + l15) * D + ks * 32 + l4 * 8];
                a2c[ni] = __builtin_amdgcn_mfma_f32_16x16x32_bf16(af, bf, a2c[ni], 0, 0, 0);
            }
        }
#pragma unroll
        for (int ni = 0; ni < 2; ++ni) {
            int col = ni * 16 + l15;
            float bb = linb[col];
#pragma unroll
            for (int r = 0; r < 4; ++r) {
                int grow = brow + w * 16 + l4 * 4 + r;
                if (grow < M) fout[(size_t)grow * OUTD + col] = a2c[ni][r] + bb;
            }
        }
    }
}

// ---------------- launch ----------------

extern "C" void kernel_launch(void* const* d_in, const int* in_sizes, int n_in,
                              void* d_out, int out_size, void* d_ws, size_t ws_size,
                              hipStream_t stream)
{
    const float* x_author = (const float*)d_in[0];
    const float* x_paper  = (const float*)d_in[1];
    const int*   e_w      = (const int*)d_in[2];
    const int*   e_wb     = (const int*)d_in[3];
    const int*   e_c      = (const int*)d_in[4];
    const float* Wl       = (const float*)d_in[5];
    const float* bl       = (const float*)d_in[6];
    const float* Wr       = (const float*)d_in[7];
    const float* linW     = (const float*)d_in[8];
    const float* linb     = (const float*)d_in[9];
    float* out = (float*)d_out;

    // ---- workspace ----
    int* ib      = (int*)d_ws;
    int* cnt     = ib;                 // 150000
    int* cursor  = ib + 150000;        // 150000
    int* S       = ib + 300000;        // 150001
    int* bsum    = ib + 450016;        // 256
    int* csr     = ib + 450304;        // 2400000
    float* bsum_p = (float*)(ib + 2850304);     // 128
    ushort* ub   = (ushort*)(ib + 2850432);     // 16B aligned
    ushort* wt    = ub;                         // 8 * 16384
    ushort* xb_a  = ub + 131072;
    ushort* xb_p  = xb_a + (size_t)NA * D;
    ushort* aggw  = xb_p + (size_t)NP * D;
    ushort* aggc  = aggw + (size_t)NP * D;
    ushort* aggwb = aggc + (size_t)NP * D;
    ushort* p1b   = aggwb + (size_t)NA * D;
    ushort* a1b   = p1b + (size_t)NP * D;
    ushort* g2b   = aggw;   // reuse: aggw consumed by paper GEMM before layer-1 gather

    hipMemsetAsync(ib, 0, 300000 * sizeof(int), stream);

    // prep (independent of CSR)
    cvt_x_kernel<<<(2 * NA * D / 4 + 255) / 256, 256, 0, stream>>>(x_author, x_paper, xb_a, xb_p);
    prep_w_kernel<<<465, 256, 0, stream>>>(Wl, Wr, linW, bl, wt, bsum_p);

    // CSR build
    int eb = (NE + 255) / 256;
    count_kernel<<<eb, 256, 0, stream>>>(e_w + NE, cnt + 0 * 50000, NE);
    count_kernel<<<eb, 256, 0, stream>>>(e_c + NE, cnt + 1 * 50000, NE);
    count_kernel<<<eb, 256, 0, stream>>>(e_wb + NE, cnt + 2 * 50000, NE);
    int nb = (NSEG + 1023) / 1024;
    scanA<<<nb, 1024, 0, stream>>>(cnt, S, bsum, NSEG);
    scanB<<<1, 256, 0, stream>>>(bsum, nb);
    scanC<<<nb, 1024, 0, stream>>>(S, bsum, NSEG, 3 * NE);
    fill_kernel<<<eb, 256, 0, stream>>>(e_w, e_w + NE, S + 0 * 50000, cursor + 0 * 50000, csr, NE);
    fill_kernel<<<eb, 256, 0, stream>>>(e_c, e_c + NE, S + 1 * 50000, cursor + 1 * 50000, csr, NE);
    fill_kernel<<<eb, 256, 0, stream>>>(e_wb, e_wb + NE, S + 2 * 50000, cursor + 2 * 50000, csr, NE);

    // layer-0 gathers (bf16)
    int gbl = (50000 * 64 + 255) / 256;
    gather_bf16<<<gbl, 256, 0, stream>>>(xb_a, S + 0 * 50000, csr, aggw, NP);
    gather_bf16<<<gbl, 256, 0, stream>>>(xb_p, S + 1 * 50000, csr, aggc, NP);
    gather_bf16<<<gbl, 256, 0, stream>>>(xb_p, S + 2 * 50000, csr, aggwb, NA);

    int gb = (50000 + 63) / 64;
    // p1 = lrelu(aggw@Wl00 + aggc@Wl02 + x_p@(Wr00+Wr02) + bl00+bl02)
    gemm_mfma<<<gb, 256, 0, stream>>>(aggw, wt + 0 * DD, aggc, wt + 1 * DD, xb_p, wt + 2 * DD,
                                      3, bsum_p, p1b, nullptr, nullptr, nullptr, NP);
    // a1 = lrelu(aggwb@Wl01 + x_a@Wr01 + bl01)
    gemm_mfma<<<gb, 256, 0, stream>>>(aggwb, wt + 3 * DD, xb_a, wt + 4 * DD, nullptr, nullptr,
                                      2, bl + 1 * D, a1b, nullptr, nullptr, nullptr, NA);

    // layer-1 gather of p1 over written_by
    gather_bf16<<<gbl, 256, 0, stream>>>(p1b, S + 2 * 50000, csr, g2b, NA);

    // a2 = lrelu(g2@Wl11 + a1@Wr11 + bl11);  out = a2 @ linW + linb  (fused)
    gemm_mfma<<<gb, 256, 0, stream>>>(g2b, wt + 5 * DD, a1b, wt + 6 * DD, nullptr, nullptr,
                                      2, bl + 4 * D, p1b /*unused*/, wt + 7 * DD, linb, out, NA);
}

// Round 4
// 357.689 us; speedup vs baseline: 8.3222x; 1.3285x over previous
//
#include <hip/hip_runtime.h>

#define NA 50000
#define NP 50000
#define NE 800000
#define D 128
#define OUTD 32
#define NSEG 150000
#define DD (D * D)

typedef float f32x4 __attribute__((ext_vector_type(4)));
typedef short s16x8 __attribute__((ext_vector_type(8)));

__device__ __forceinline__ ushort f2b(float f) {
    uint x = __float_as_uint(f);
    x += ((x >> 16) & 1u) + 0x7fffu;   // round-to-nearest-even
    return (ushort)(x >> 16);
}

// ---------------- CSR build (fused count+pos, then place) ----------------

__global__ __launch_bounds__(256) void count_all(
    const int* __restrict__ d0, const int* __restrict__ d1, const int* __restrict__ d2,
    int* __restrict__ cnt, int* __restrict__ pos)
{
    int i = blockIdx.x * 256 + threadIdx.x;
    if (i >= 3 * NE) return;
    int r = (i >= NE) + (i >= 2 * NE);
    int e = i - r * NE;
    const int* dp = (r == 0) ? d0 : ((r == 1) ? d1 : d2);
    int d = dp[e];
    pos[i] = atomicAdd(&cnt[r * 50000 + d], 1);
}

__global__ __launch_bounds__(256) void place_all(
    const int* __restrict__ s0, const int* __restrict__ s1, const int* __restrict__ s2,
    const int* __restrict__ d0, const int* __restrict__ d1, const int* __restrict__ d2,
    const int* __restrict__ rowptr, const int* __restrict__ pos, int* __restrict__ csr)
{
    int i = blockIdx.x * 256 + threadIdx.x;
    if (i >= 3 * NE) return;
    int r = (i >= NE) + (i >= 2 * NE);
    int e = i - r * NE;
    const int* sp = (r == 0) ? s0 : ((r == 1) ? s1 : s2);
    const int* dp = (r == 0) ? d0 : ((r == 1) ? d1 : d2);
    int d = dp[e];
    csr[rowptr[r * 50000 + d] + pos[i]] = sp[e];
}

// ---------------- scan (exclusive, over 150k concatenated counts) ----------------

__global__ __launch_bounds__(1024) void scanA(
    const int* __restrict__ cnt, int* __restrict__ S, int* __restrict__ bsum, int n)
{
    __shared__ int wsum[16];
    int t = threadIdx.x;
    int gi = blockIdx.x * 1024 + t;
    int v = (gi < n) ? cnt[gi] : 0;
    int lane = t & 63, wid = t >> 6;
    int x = v;
#pragma unroll
    for (int off = 1; off < 64; off <<= 1) {
        int y = __shfl_up(x, off, 64);
        if (lane >= off) x += y;
    }
    if (lane == 63) wsum[wid] = x;
    __syncthreads();
    if (wid == 0) {
        int w = (lane < 16) ? wsum[lane] : 0;
#pragma unroll
        for (int off = 1; off < 16; off <<= 1) {
            int y = __shfl_up(w, off, 64);
            if (lane >= off) w += y;
        }
        if (lane < 16) wsum[lane] = w;
    }
    __syncthreads();
    int woff = (wid > 0) ? wsum[wid - 1] : 0;
    int incl = x + woff;
    if (gi < n) S[gi] = incl - v;
    if (t == 1023) bsum[blockIdx.x] = incl;
}

__global__ __launch_bounds__(256) void scanB(int* __restrict__ bsum, int nb)
{
    __shared__ int sh[256];
    int t = threadIdx.x;
    int v = (t < nb) ? bsum[t] : 0;
    sh[t] = v;
    __syncthreads();
    for (int off = 1; off < 256; off <<= 1) {
        int y = (t >= off) ? sh[t - off] : 0;
        __syncthreads();
        sh[t] += y;
        __syncthreads();
    }
    if (t < nb) bsum[t] = sh[t] - v;
}

__global__ __launch_bounds__(1024) void scanC(
    int* __restrict__ S, const int* __restrict__ bsum, int n, int total)
{
    int gi = blockIdx.x * 1024 + threadIdx.x;
    if (gi < n) S[gi] += bsum[blockIdx.x];
    if (gi == 0) S[n] = total;
}

// ---------------- prep: x -> bf16 ----------------

__global__ __launch_bounds__(256) void cvt_x_kernel(
    const float* __restrict__ xa, const float* __restrict__ xp,
    ushort* __restrict__ oa, ushort* __restrict__ op)
{
    int i = blockIdx.x * 256 + threadIdx.x;   // float4 index
    const int per = NA * D / 4;
    const float* src; ushort* dst; int li;
    if (i < per) { src = xa; dst = oa; li = i; }
    else { src = xp; dst = op; li = i - per; }
    float4 v = *(const float4*)&src[(size_t)li * 4];
    ushort4 o;
    o.x = f2b(v.x); o.y = f2b(v.y); o.z = f2b(v.z); o.w = f2b(v.w);
    *(ushort4*)&dst[(size_t)li * 4] = o;
}

// ---------------- prep: weights -> bf16 transposed ----------------

__global__ __launch_bounds__(256) void prep_w_kernel(
    const float* __restrict__ Wl, const float* __restrict__ Wr,
    const float* __restrict__ linW, const float* __restrict__ bl,
    ushort* __restrict__ wt, float* __restrict__ bsum_p)
{
    int b = blockIdx.x, t = threadIdx.x;
    if (b < 448) {
        int job = b >> 6;
        int idx = (b & 63) * 256 + t;
        int n = idx >> 7, k = idx & 127;
        const float* src;
        float add = 0.f;
        switch (job) {
            case 0: src = Wl + 0 * DD; break;
            case 1: src = Wl + 2 * DD; break;
            case 2: src = Wr + 0 * DD; add = Wr[2 * DD + k * D + n]; break;
            case 3: src = Wl + 1 * DD; break;
            case 4: src = Wr + 1 * DD; break;
            case 5: src = Wl + 4 * DD; break;
            default: src = Wr + 4 * DD; break;
        }
        wt[(size_t)job * DD + idx] = f2b(src[k * D + n] + add);
    } else if (b < 464) {
        int idx = (b - 448) * 256 + t;    // linW^T: n<32, k<128
        int n = idx >> 7, k = idx & 127;
        wt[(size_t)7 * DD + idx] = f2b(linW[k * OUTD + n]);
    } else {
        if (t < D) bsum_p[t] = bl[t] + bl[2 * D + t];
    }
}

// ---------------- gather-mean (bf16 in/out, f32 accum) ----------------
// merged layer-0 gather: wid in [0,150000): seg0 writes(a->p), seg1 cites(p->p),
// seg2 written_by(p->a); outputs contiguous agg3[150000][D]

__global__ __launch_bounds__(256) void gather3(
    const ushort* __restrict__ xa, const ushort* __restrict__ xp,
    const int* __restrict__ rowptr, const int* __restrict__ csr,
    ushort* __restrict__ agg3)
{
    int wid = (blockIdx.x * 256 + threadIdx.x) >> 6;
    if (wid >= NSEG) return;
    const ushort* x = (wid < 50000) ? xa : xp;
    int lane = threadIdx.x & 63;
    int beg = __builtin_amdgcn_readfirstlane(rowptr[wid]);
    int end = __builtin_amdgcn_readfirstlane(rowptr[wid + 1]);
    float ax = 0.f, ay = 0.f, bx = 0.f, by = 0.f;
    int j = beg;
    for (; j + 4 <= end; j += 4) {
        int s0 = csr[j], s1 = csr[j + 1], s2 = csr[j + 2], s3 = csr[j + 3];
        uint u0 = *(const uint*)&x[(size_t)s0 * D + lane * 2];
        uint u1 = *(const uint*)&x[(size_t)s1 * D + lane * 2];
        uint u2 = *(const uint*)&x[(size_t)s2 * D + lane * 2];
        uint u3 = *(const uint*)&x[(size_t)s3 * D + lane * 2];
        ax += __uint_as_float(u0 << 16); ay += __uint_as_float(u0 & 0xffff0000u);
        bx += __uint_as_float(u1 << 16); by += __uint_as_float(u1 & 0xffff0000u);
        ax += __uint_as_float(u2 << 16); ay += __uint_as_float(u2 & 0xffff0000u);
        bx += __uint_as_float(u3 << 16); by += __uint_as_float(u3 & 0xffff0000u);
    }
    for (; j < end; ++j) {
        int s0 = csr[j];
        uint u0 = *(const uint*)&x[(size_t)s0 * D + lane * 2];
        ax += __uint_as_float(u0 << 16); ay += __uint_as_float(u0 & 0xffff0000u);
    }
    float sc = (end > beg) ? 1.0f / (float)(end - beg) : 0.f;
    float rx = (ax + bx) * sc, ry = (ay + by) * sc;
    uint pk = (uint)f2b(rx) | ((uint)f2b(ry) << 16);
    *(uint*)&agg3[(size_t)wid * D + lane * 2] = pk;
}

// single-relation gather (layer 1)
__global__ __launch_bounds__(256) void gather_bf16(
    const ushort* __restrict__ x, const int* __restrict__ rowptr,
    const int* __restrict__ csr, ushort* __restrict__ out, int n)
{
    int wid = (blockIdx.x * 256 + threadIdx.x) >> 6;
    if (wid >= n) return;
    int lane = threadIdx.x & 63;
    int beg = __builtin_amdgcn_readfirstlane(rowptr[wid]);
    int end = __builtin_amdgcn_readfirstlane(rowptr[wid + 1]);
    float ax = 0.f, ay = 0.f, bx = 0.f, by = 0.f;
    int j = beg;
    for (; j + 4 <= end; j += 4) {
        int s0 = csr[j], s1 = csr[j + 1], s2 = csr[j + 2], s3 = csr[j + 3];
        uint u0 = *(const uint*)&x[(size_t)s0 * D + lane * 2];
        uint u1 = *(const uint*)&x[(size_t)s1 * D + lane * 2];
        uint u2 = *(const uint*)&x[(size_t)s2 * D + lane * 2];
        uint u3 = *(const uint*)&x[(size_t)s3 * D + lane * 2];
        ax += __uint_as_float(u0 << 16); ay += __uint_as_float(u0 & 0xffff0000u);
        bx += __uint_as_float(u1 << 16); by += __uint_as_float(u1 & 0xffff0000u);
        ax += __uint_as_float(u2 << 16); ay += __uint_as_float(u2 & 0xffff0000u);
        bx += __uint_as_float(u3 << 16); by += __uint_as_float(u3 & 0xffff0000u);
    }
    for (; j < end; ++j) {
        int s0 = csr[j];
        uint u0 = *(const uint*)&x[(size_t)s0 * D + lane * 2];
        ax += __uint_as_float(u0 << 16); ay += __uint_as_float(u0 & 0xffff0000u);
    }
    float sc = (end > beg) ? 1.0f / (float)(end - beg) : 0.f;
    float rx = (ax + bx) * sc, ry = (ay + by) * sc;
    uint pk = (uint)f2b(rx) | ((uint)f2b(ry) << 16);
    *(uint*)&out[(size_t)wid * D + lane * 2] = pk;
}

// ---------------- MFMA bf16 multi-segment GEMM ----------------

#define LDA 136

__global__ __launch_bounds__(256) void gemm_mfma(
    const ushort* __restrict__ A0, const ushort* __restrict__ WT0,
    const ushort* __restrict__ A1, const ushort* __restrict__ WT1,
    const ushort* __restrict__ A2, const ushort* __restrict__ WT2,
    int nseg, const float* __restrict__ bias,
    ushort* __restrict__ C,
    const ushort* __restrict__ linWT, const float* __restrict__ linb,
    float* __restrict__ fout, int M)
{
    __shared__ ushort As[64 * LDA];

    const int t = threadIdx.x;
    const int w = t >> 6;
    const int l = t & 63;
    const int wr = w >> 1, wc = w & 1;
    const int l15 = l & 15, l4 = l >> 4;
    const int brow = blockIdx.x * 64;

    f32x4 acc[2][4];
#pragma unroll
    for (int i = 0; i < 2; ++i)
#pragma unroll
        for (int j = 0; j < 4; ++j) acc[i][j] = (f32x4){0.f, 0.f, 0.f, 0.f};

    for (int s = 0; s < nseg; ++s) {
        const ushort* A = (s == 0) ? A0 : ((s == 1) ? A1 : A2);
        const ushort* WT = (s == 0) ? WT0 : ((s == 1) ? WT1 : WT2);

        if (s) __syncthreads();
#pragma unroll
        for (int it = 0; it < 4; ++it) {
            int f = it * 256 + t;
            int row = f >> 4, cc = f & 15;
            int grow = brow + row;
            float4 v = make_float4(0.f, 0.f, 0.f, 0.f);
            if (grow < M) v = *(const float4*)&A[(size_t)grow * D + cc * 8];
            *(float4*)&As[row * LDA + cc * 8] = v;
        }
        s16x8 Bf[4][4];
#pragma unroll
        for (int ni = 0; ni < 4; ++ni)
#pragma unroll
            for (int ks = 0; ks < 4; ++ks)
                Bf[ni][ks] = *(const s16x8*)&WT[(size_t)(wc * 64 + ni * 16 + l15) * D + ks * 32 + l4 * 8];
        __syncthreads();

#pragma unroll
        for (int ks = 0; ks < 4; ++ks) {
            s16x8 af[2];
#pragma unroll
            for (int mi = 0; mi < 2; ++mi)
                af[mi] = *(const s16x8*)&As[(wr * 32 + mi * 16 + l15) * LDA + ks * 32 + l4 * 8];
#pragma unroll
            for (int mi = 0; mi < 2; ++mi)
#pragma unroll
                for (int ni = 0; ni < 4; ++ni)
                    acc[mi][ni] = __builtin_amdgcn_mfma_f32_16x16x32_bf16(
                        af[mi], Bf[ni][ks], acc[mi][ni], 0, 0, 0);
        }
    }

    if (!fout) {
#pragma unroll
        for (int mi = 0; mi < 2; ++mi) {
#pragma unroll
            for (int ni = 0; ni < 4; ++ni) {
                int col = wc * 64 + ni * 16 + l15;
                float bb = bias[col];
#pragma unroll
                for (int r = 0; r < 4; ++r) {
                    int grow = brow + wr * 32 + mi * 16 + l4 * 4 + r;
                    if (grow >= M) continue;
                    float v = acc[mi][ni][r] + bb;
                    v = v > 0.f ? v : 0.01f * v;
                    C[(size_t)grow * D + col] = f2b(v);
                }
            }
        }
    } else {
        __syncthreads();
#pragma unroll
        for (int mi = 0; mi < 2; ++mi) {
#pragma unroll
            for (int ni = 0; ni < 4; ++ni) {
                int col = wc * 64 + ni * 16 + l15;
                float bb = bias[col];
#pragma unroll
                for (int r = 0; r < 4; ++r) {
                    int row = wr * 32 + mi * 16 + l4 * 4 + r;
                    float v = acc[mi][ni][r] + bb;
                    v = v > 0.f ? v : 0.01f * v;
                    As[row * LDA + col] = f2b(v);
                }
            }
        }
        __syncthreads();
        f32x4 a2c[2];
        a2c[0] = (f32x4){0.f, 0.f, 0.f, 0.f};
        a2c[1] = (f32x4){0.f, 0.f, 0.f, 0.f};
#pragma unroll
        for (int ks = 0; ks < 4; ++ks) {
            s16x8 af = *(const s16x8*)&As[(w * 16 + l15) * LDA + ks * 32 + l4 * 8];
#pragma unroll
            for (int ni = 0; ni < 2; ++ni) {
                s16x8 bf = *(const s16x8*)&linWT[(size_t)(ni * 16 + l15) * D + ks * 32 + l4 * 8];
                a2c[ni] = __builtin_amdgcn_mfma_f32_16x16x32_bf16(af, bf, a2c[ni], 0, 0, 0);
            }
        }
#pragma unroll
        for (int ni = 0; ni < 2; ++ni) {
            int col = ni * 16 + l15;
            float bb = linb[col];
#pragma unroll
            for (int r = 0; r < 4; ++r) {
                int grow = brow + w * 16 + l4 * 4 + r;
                if (grow < M) fout[(size_t)grow * OUTD + col] = a2c[ni][r] + bb;
            }
        }
    }
}

// ---------------- launch ----------------

extern "C" void kernel_launch(void* const* d_in, const int* in_sizes, int n_in,
                              void* d_out, int out_size, void* d_ws, size_t ws_size,
                              hipStream_t stream)
{
    const float* x_author = (const float*)d_in[0];
    const float* x_paper  = (const float*)d_in[1];
    const int*   e_w      = (const int*)d_in[2];
    const int*   e_wb     = (const int*)d_in[3];
    const int*   e_c      = (const int*)d_in[4];
    const float* Wl       = (const float*)d_in[5];
    const float* bl       = (const float*)d_in[6];
    const float* Wr       = (const float*)d_in[7];
    const float* linW     = (const float*)d_in[8];
    const float* linb     = (const float*)d_in[9];
    float* out = (float*)d_out;

    // ---- workspace (ints) ----
    int* ib   = (int*)d_ws;
    int* cnt  = ib;                  // 150000
    int* S    = ib + 150016;         // 150001
    int* bsum = ib + 300032;         // 256
    int* pos  = ib + 300544;         // 2400000
    int* csr  = ib + 2700544;        // 2400000
    float* bsum_p = (float*)(ib + 5100544);  // 128
    ushort* ub    = (ushort*)(ib + 5100672); // 16B aligned
    ushort* wt    = ub;                        // 8*16384
    ushort* xb_a  = ub + 131072;
    ushort* xb_p  = xb_a + (size_t)NA * D;
    ushort* agg3  = xb_p + (size_t)NP * D;     // [150000][D]: aggw|aggc|aggwb
    ushort* aggw  = agg3;
    ushort* aggwb = agg3 + (size_t)100000 * D;
    ushort* p1b   = agg3 + (size_t)NSEG * D;
    ushort* a1b   = p1b + (size_t)NP * D;
    ushort* g2b   = aggw;   // reuse after paper GEMM consumed aggw/aggc

    hipMemsetAsync(cnt, 0, 150000 * sizeof(int), stream);

    // prep (independent)
    cvt_x_kernel<<<(2 * NA * D / 4 + 255) / 256, 256, 0, stream>>>(x_author, x_paper, xb_a, xb_p);
    prep_w_kernel<<<465, 256, 0, stream>>>(Wl, Wr, linW, bl, wt, bsum_p);

    // CSR build: fused count+pos, scan, place (no atomics)
    int eb3 = (3 * NE + 255) / 256;
    count_all<<<eb3, 256, 0, stream>>>(e_w + NE, e_c + NE, e_wb + NE, cnt, pos);
    int nb = (NSEG + 1023) / 1024;
    scanA<<<nb, 1024, 0, stream>>>(cnt, S, bsum, NSEG);
    scanB<<<1, 256, 0, stream>>>(bsum, nb);
    scanC<<<nb, 1024, 0, stream>>>(S, bsum, NSEG, 3 * NE);
    place_all<<<eb3, 256, 0, stream>>>(e_w, e_c, e_wb,
                                       e_w + NE, e_c + NE, e_wb + NE,
                                       S, pos, csr);

    // layer-0 gathers, merged (150000 waves)
    int gbl3 = (NSEG * 64 + 255) / 256;
    gather3<<<gbl3, 256, 0, stream>>>(xb_a, xb_p, S, csr, agg3);

    int gb = (50000 + 63) / 64;
    // p1 = lrelu(aggw@Wl00 + aggc@Wl02 + x_p@(Wr00+Wr02) + bl00+bl02)
    gemm_mfma<<<gb, 256, 0, stream>>>(aggw, wt + 0 * DD, aggw + (size_t)50000 * D, wt + 1 * DD,
                                      xb_p, wt + 2 * DD,
                                      3, bsum_p, p1b, nullptr, nullptr, nullptr, NP);
    // a1 = lrelu(aggwb@Wl01 + x_a@Wr01 + bl01)
    gemm_mfma<<<gb, 256, 0, stream>>>(aggwb, wt + 3 * DD, xb_a, wt + 4 * DD, nullptr, nullptr,
                                      2, bl + 1 * D, a1b, nullptr, nullptr, nullptr, NA);

    // layer-1 gather of p1 over written_by
    int gbl = (50000 * 64 + 255) / 256;
    gather_bf16<<<gbl, 256, 0, stream>>>(p1b, S + 100000, csr, g2b, NA);

    // a2 = lrelu(g2@Wl11 + a1@Wr11 + bl11);  out = a2 @ linW + linb (fused)
    gemm_mfma<<<gb, 256, 0, stream>>>(g2b, wt + 5 * DD, a1b, wt + 6 * DD, nullptr, nullptr,
                                      2, bl + 4 * D, nullptr, wt + 7 * DD, linb, out, NA);
}